// Round 1
// baseline (434.107 us; speedup 1.0000x reference)
//
#include <hip/hip_runtime.h>

// FrameDropout: out[b,d,t] = x[b,d,t] * (u[t] >= 0.2f ? 1 : 0)
// x: [32, 512, 4096] f32 (T innermost), u: [4096] f32, out same shape as x.
// Memory-bound streaming op: float4-vectorized grid-stride loop.

#define DROPOUT_PROB 0.2f
#define T_DIV4 1024u  // 4096 / 4

__global__ void FrameDropout_kernel(const float4* __restrict__ x,
                                    const float4* __restrict__ u4,
                                    float4* __restrict__ out,
                                    unsigned int n4) {
    const unsigned int stride = gridDim.x * blockDim.x;
    for (unsigned int i = blockIdx.x * blockDim.x + threadIdx.x; i < n4; i += stride) {
        float4 xv = x[i];
        float4 uv = u4[i & (T_DIV4 - 1u)];  // frame index = i % (T/4), aligned float4 of u
        float4 o;
        o.x = (uv.x >= DROPOUT_PROB) ? xv.x : 0.0f;
        o.y = (uv.y >= DROPOUT_PROB) ? xv.y : 0.0f;
        o.z = (uv.z >= DROPOUT_PROB) ? xv.z : 0.0f;
        o.w = (uv.w >= DROPOUT_PROB) ? xv.w : 0.0f;
        out[i] = o;
    }
}

extern "C" void kernel_launch(void* const* d_in, const int* in_sizes, int n_in,
                              void* d_out, int out_size, void* d_ws, size_t ws_size,
                              hipStream_t stream) {
    const float4* x  = (const float4*)d_in[0];   // [32,512,4096] f32
    const float4* u4 = (const float4*)d_in[1];   // [4096] f32 viewed as float4[1024]
    float4* out = (float4*)d_out;

    const unsigned int n4 = (unsigned int)(out_size / 4);  // 67108864/4 = 16777216
    const int block = 256;
    // Cap grid at ~2048 blocks (8 blocks/CU on 256 CUs), grid-stride the rest.
    unsigned int blocks = (n4 + block - 1) / block;
    if (blocks > 2048u) blocks = 2048u;

    FrameDropout_kernel<<<dim3(blocks), dim3(block), 0, stream>>>(x, u4, out, n4);
}